// Round 4
// baseline (1347.268 us; speedup 1.0000x reference)
//
#include <hip/hip_runtime.h>
#include <hip/hip_bf16.h>
#include <math.h>

typedef __bf16 bf16;
typedef __bf16 bf16x4 __attribute__((ext_vector_type(4)));
typedef __bf16 bf16x8 __attribute__((ext_vector_type(8)));
typedef float f32x4 __attribute__((ext_vector_type(4)));

#define OCC 230
#define NRELS 53
// ws layout (bf16 elems)
#define PCAT_OFF 2500000   // 61*61*10 = 37210
#define REMBB_OFF 2537216  // 64*704 = 45056 (rows>=53, cols>=690 zero)
#define CONVB_OFF 2582272  // 256*192 = 49152 (oc>=230, k>=180 zero)
#define ZOFF 2631424       // 8 zeros
#define WS_ELEMS 2631432

union FragU { bf16x8 v8; bf16x4 v4[2]; bf16 e[8]; };

// ---- prep: convert/pad everything to bf16 in ws ----
__global__ void pcnn_prep(const float* __restrict__ w2v, const float* __restrict__ p1e,
                          const float* __restrict__ p2e, const float* __restrict__ remb,
                          const float* __restrict__ convw, bf16* __restrict__ wsb) {
  const int i = blockIdx.x * 256 + threadIdx.x;
  if (i < 625000) {
    const float4 f = *reinterpret_cast<const float4*>(w2v + 4 * i);
    bf16x4 v = {(bf16)f.x, (bf16)f.y, (bf16)f.z, (bf16)f.w};
    *reinterpret_cast<bf16x4*>(wsb + 4 * i) = v;
    return;
  }
  int e = i - 625000;
  if (e < 37210) {
    const int row = e / 10, c = e - row * 10;
    const int v1 = row / 61, v2 = row - v1 * 61;
    wsb[PCAT_OFF + e] = (bf16)((c < 5) ? p1e[v1 * 5 + c] : p2e[v2 * 5 + (c - 5)]);
    return;
  }
  e -= 37210;
  if (e < 45056) {
    const int r = e / 704, c = e - r * 704;
    wsb[REMBB_OFF + e] = (r < NRELS && c < 690) ? (bf16)remb[r * 690 + c] : (bf16)0.0f;
    return;
  }
  e -= 45056;
  if (e < 49152) {
    const int oc = e / 192, k = e - oc * 192;
    wsb[CONVB_OFF + e] = (oc < OCC && k < 180) ? (bf16)convw[oc * 180 + k] : (bf16)0.0f;
    return;
  }
  e -= 49152;
  if (e < 8) wsb[ZOFF + e] = (bf16)0.0f;
}

__global__ __launch_bounds__(512, 6)
void pcnn_bag(const int* __restrict__ words, const int* __restrict__ posi,
              const float* __restrict__ cb0, const float* __restrict__ cb1,
              const float* __restrict__ cb2, const float* __restrict__ rbias,
              const bf16* __restrict__ wsb, float* __restrict__ out)
{
  __shared__ __align__(16) bf16 xflat[2][7360];   // A[m][k] = xflat[m*60+k] (+60 lead pad)
  __shared__ __align__(16) bf16 fl_all[8][712];   // tanh feats per sentence (cols>=690 zero)
  __shared__ int widx[960];                       // word | pidx<<16 | piece<<28
  __shared__ float poolbuf[2][3][256];
  __shared__ float logits_l[8][64];

  const int t = threadIdx.x;
  const int b = blockIdx.x;
  const int wv = t >> 6;       // 0..7
  const int lane = t & 63;
  const int g = lane >> 4;
  const int cl = lane & 15;
  const int mh = wv >> 2;      // m-half: rows [mh*64, mh*64+64)
  const int nq = wv & 3;       // oc-quad: tiles nq*4 .. nq*4+3

  // ---- ids for the whole bag ----
  for (int i = t; i < 960; i += 512) {
    const int w = words[b * 960 + i];
    const int2 pp = *reinterpret_cast<const int2*>(posi + b * 1920 + 2 * i);
    const bool b0 = pp.x >= 30, b1 = pp.y >= 30;
    const int pc = (b0 && b1) ? 0 : ((!b0 && !b1) ? 2 : 1);
    widx[i] = w | ((pp.x * 61 + pp.y) << 16) | (pc << 28);
  }
  if (t < 60) { xflat[0][t] = (bf16)0.0f; xflat[1][t] = (bf16)0.0f; }
  if (t < 112) fl_all[t / 14][690 + (t % 14)] = (bf16)0.0f;

  // ---- conv weights (pre-padded bf16) -> registers ----
  FragU Bf[4][6];
  {
    const bf16* cwb = wsb + CONVB_OFF;
#pragma unroll
    for (int nt = 0; nt < 4; ++nt) {
      const int oc = (nq * 4 + nt) * 16 + cl;
#pragma unroll
      for (int ks = 0; ks < 6; ++ks)
        Bf[nt][ks].v8 = *reinterpret_cast<const bf16x8*>(cwb + oc * 192 + ks * 32 + g * 8);
    }
  }

  // ---- per-thread bias/slot precompute for combine phase ----
  int pA = 0, ocA = 0, pB = 0, ocB = 0;
  float biasA = 0.0f, biasB = 0.0f;
  if (t < 690) {
    pA = t / 230; ocA = t - pA * 230;
    biasA = (pA == 0 ? cb0 : pA == 1 ? cb1 : cb2)[ocA];
  }
  if (t + 512 < 690) {
    const int t2 = t + 512;
    pB = t2 / 230; ocB = t2 - pB * 230;
    biasB = (pB == 0 ? cb0 : pB == 1 ? cb1 : cb2)[ocB];
  }
  __syncthreads();  // widx ready

  // ---- async gather: sentence s -> xflat[nb]; tail lanes fetch zeros ----
  auto gather_one = [&](int s, int nb, int j) {
    const int q = j * 512 + wv * 64 + lane;        // bf16-pair slot; dst elem = 60+2q
    const int qc = (q < 3600) ? q : 3599;
    const int l = qc / 30;
    const int c = qc - l * 30;
    const int wi = widx[s * 120 + l];
    const int word = wi & 0xFFFF;
    const int pidx = (wi >> 16) & 0xFFF;
    const bf16* srcd = (c < 25) ? (wsb + word * 50 + 2 * c)
                                : (wsb + PCAT_OFF + pidx * 10 + (2 * c - 50));
    const bf16* src = (q < 3600) ? srcd : (wsb + ZOFF);
    bf16* dst = &xflat[nb][60 + j * 1024 + wv * 128];  // wave-uniform; HW adds lane*4B
    __builtin_amdgcn_global_load_lds(
        (const __attribute__((address_space(1))) void*)src,
        (__attribute__((address_space(3))) void*)dst, 4, 0, 0);
  };
  auto issue_gather = [&](int s, int nb) {
#pragma unroll
    for (int j = 0; j < 7; ++j) gather_one(s, nb, j);
    if (wv == 0) gather_one(s, nb, 7);   // covers data tail + writes zero pad [7260,7355]
  };

  issue_gather(0, 0);
  asm volatile("s_waitcnt vmcnt(0)" ::: "memory");
  __syncthreads();

  // ---- per-sentence: conv GEMM + piecewise pool + tanh ----
  for (int s = 0; s < 8; ++s) {
    const int nb = s & 1;
    if (s < 7) issue_gather(s + 1, nb ^ 1);

    int mrow[4];
#pragma unroll
    for (int mt = 0; mt < 4; ++mt) {
      const int m = (mh * 4 + mt) * 16 + cl;
      mrow[mt] = (m < 120 ? m : 119) * 60;   // clamp pad rows in-bounds (outputs discarded)
    }

    f32x4 acc[4][4];
    const f32x4 z4 = {0.f, 0.f, 0.f, 0.f};
#pragma unroll
    for (int mt = 0; mt < 4; ++mt)
#pragma unroll
      for (int nt = 0; nt < 4; ++nt) acc[mt][nt] = z4;

#pragma unroll
    for (int ks = 0; ks < 6; ++ks) {
      FragU a[4];
#pragma unroll
      for (int mt = 0; mt < 4; ++mt) {
        const int idx = mrow[mt] + ks * 32 + g * 8;
        a[mt].v4[0] = *reinterpret_cast<const bf16x4*>(&xflat[nb][idx]);
        a[mt].v4[1] = *reinterpret_cast<const bf16x4*>(&xflat[nb][idx + 4]);
      }
#pragma unroll
      for (int mt = 0; mt < 4; ++mt)
#pragma unroll
        for (int nt = 0; nt < 4; ++nt)
          acc[mt][nt] = __builtin_amdgcn_mfma_f32_16x16x32_bf16(
              a[mt].v8, Bf[nt][ks].v8, acc[mt][nt], 0, 0, 0);
    }

    // piecewise masked max (ref semantics: masked-out contributes 0)
    float pool[4][3];
#pragma unroll
    for (int nt = 0; nt < 4; ++nt) { pool[nt][0] = pool[nt][1] = pool[nt][2] = -INFINITY; }
#pragma unroll
    for (int mt = 0; mt < 4; ++mt) {
      const int l0 = (mh * 4 + mt) * 16 + g * 4;
      if (l0 < 120) {
        const int4 pv = *reinterpret_cast<const int4*>(&widx[s * 120 + l0]);
        const int pcs[4] = {(int)((unsigned)pv.x >> 28), (int)((unsigned)pv.y >> 28),
                            (int)((unsigned)pv.z >> 28), (int)((unsigned)pv.w >> 28)};
#pragma unroll
        for (int r = 0; r < 4; ++r) {
          const int p = pcs[r];
#pragma unroll
          for (int nt = 0; nt < 4; ++nt) {
            const float v = acc[mt][nt][r];
            pool[nt][0] = fmaxf(pool[nt][0], p == 0 ? v : 0.0f);
            pool[nt][1] = fmaxf(pool[nt][1], p == 1 ? v : 0.0f);
            pool[nt][2] = fmaxf(pool[nt][2], p == 2 ? v : 0.0f);
          }
        }
      }
    }
#pragma unroll
    for (int nt = 0; nt < 4; ++nt)
#pragma unroll
      for (int p = 0; p < 3; ++p) {
        float x = pool[nt][p];
        x = fmaxf(x, __shfl_xor(x, 16));
        x = fmaxf(x, __shfl_xor(x, 32));
        pool[nt][p] = x;
      }
    if (g == 0) {
#pragma unroll
      for (int nt = 0; nt < 4; ++nt) {
        const int oc = nq * 64 + nt * 16 + cl;
        poolbuf[mh][0][oc] = pool[nt][0];
        poolbuf[mh][1][oc] = pool[nt][1];
        poolbuf[mh][2][oc] = pool[nt][2];
      }
    }
    __syncthreads();  // poolbuf ready

    if (t < 690)
      fl_all[s][t] = (bf16)tanhf(fmaxf(poolbuf[0][pA][ocA], poolbuf[1][pA][ocA]) + biasA);
    if (t + 512 < 690)
      fl_all[s][t + 512] = (bf16)tanhf(fmaxf(poolbuf[0][pB][ocB], poolbuf[1][pB][ocB]) + biasB);

    asm volatile("s_waitcnt vmcnt(0)" ::: "memory");  // gather(s+1) landed (per wave)
    __syncthreads();  // xflat[nb^1] ready, poolbuf free, fl_all[s] visible
  }

  // ---- batched logits GEMM: [8 sent x 704] @ rembb^T[704 x 64] ----
  if (wv < 4) {
    f32x4 lac = {0.f, 0.f, 0.f, 0.f};
    const bf16* brow = wsb + REMBB_OFF + (wv * 16 + cl) * 704 + g * 8;
    const bf16x8 zf = {(bf16)0.f, (bf16)0.f, (bf16)0.f, (bf16)0.f,
                       (bf16)0.f, (bf16)0.f, (bf16)0.f, (bf16)0.f};
#pragma unroll
    for (int ks = 0; ks < 22; ++ks) {
      bf16x8 afr = (cl < 8)
          ? *reinterpret_cast<const bf16x8*>(&fl_all[cl][ks * 32 + g * 8]) : zf;
      const bf16x8 bfr = *reinterpret_cast<const bf16x8*>(brow + ks * 32);
      lac = __builtin_amdgcn_mfma_f32_16x16x32_bf16(afr, bfr, lac, 0, 0, 0);
    }
    if (g < 2) {
      const int rel = wv * 16 + cl;
      const float bias = (rel < NRELS) ? rbias[rel] : 0.0f;
#pragma unroll
      for (int r = 0; r < 4; ++r)
        logits_l[g * 4 + r][rel] = lac[r] * 0.5f + bias;
    }
  }
  __syncthreads();

  // ---- per-wave softmax: wave wv handles sentence wv ----
  {
    const float x = (lane < NRELS) ? logits_l[wv][lane] : -INFINITY;
    float m = x;
#pragma unroll
    for (int off = 32; off; off >>= 1) m = fmaxf(m, __shfl_xor(m, off));
    const float e = (lane < NRELS) ? __expf(x - m) : 0.0f;
    float sm = e;
#pragma unroll
    for (int off = 32; off; off >>= 1) sm += __shfl_xor(sm, off);
    if (lane < NRELS) logits_l[wv][lane] = x - m - __logf(sm);
  }
  __syncthreads();

  // ---- fused bag-max ----
  if (t < NRELS) {
    float m = logits_l[0][t];
#pragma unroll
    for (int s2 = 1; s2 < 8; ++s2) m = fmaxf(m, logits_l[s2][t]);
    out[b * NRELS + t] = m;
  }
}

extern "C" void kernel_launch(void* const* d_in, const int* in_sizes, int n_in,
                              void* d_out, int out_size, void* d_ws, size_t ws_size,
                              hipStream_t stream) {
  const int* words  = (const int*)d_in[0];
  const int* posi   = (const int*)d_in[1];
  const float* w2v  = (const float*)d_in[2];
  const float* p1e  = (const float*)d_in[3];
  const float* p2e  = (const float*)d_in[4];
  const float* cw   = (const float*)d_in[5];
  const float* cb0  = (const float*)d_in[6];
  const float* cb1  = (const float*)d_in[7];
  const float* cb2  = (const float*)d_in[8];
  const float* remb = (const float*)d_in[9];
  const float* rbias= (const float*)d_in[10];
  bf16* wsb = (bf16*)d_ws;
  float* out = (float*)d_out;

  pcnn_prep<<<2955, 256, 0, stream>>>(w2v, p1e, p2e, remb, cw, wsb);
  pcnn_bag<<<1000, 512, 0, stream>>>(words, posi, cb0, cb1, cb2, rbias, wsb, out);
}

// Round 5
// 280.661 us; speedup vs baseline: 4.8003x; 4.8003x over previous
//
#include <hip/hip_runtime.h>
#include <hip/hip_bf16.h>
#include <math.h>

typedef __bf16 bf16;
typedef __bf16 bf16x4 __attribute__((ext_vector_type(4)));
typedef __bf16 bf16x8 __attribute__((ext_vector_type(8)));
typedef float f32x4 __attribute__((ext_vector_type(4)));

#define OCC 230
#define NRELS 53
// ws layout (bf16 elems)
#define PCAT_OFF 2500000   // 61*61*10 = 37210
#define REMBB_OFF 2537216  // 64*704 = 45056 (rows>=53, cols>=690 zero)
#define CONVB_OFF 2582272  // 256*192 = 49152 (oc>=230, k>=180 zero)
#define ZOFF 2631424       // 8 zeros
#define WS_ELEMS 2631432

union FragU { bf16x8 v8; bf16x4 v4[2]; bf16 e[8]; };

// ---- prep: convert/pad everything to bf16 in ws ----
__global__ void pcnn_prep(const float* __restrict__ w2v, const float* __restrict__ p1e,
                          const float* __restrict__ p2e, const float* __restrict__ remb,
                          const float* __restrict__ convw, bf16* __restrict__ wsb) {
  const int i = blockIdx.x * 256 + threadIdx.x;
  if (i < 625000) {
    const float4 f = *reinterpret_cast<const float4*>(w2v + 4 * i);
    bf16x4 v = {(bf16)f.x, (bf16)f.y, (bf16)f.z, (bf16)f.w};
    *reinterpret_cast<bf16x4*>(wsb + 4 * i) = v;
    return;
  }
  int e = i - 625000;
  if (e < 37210) {
    const int row = e / 10, c = e - row * 10;
    const int v1 = row / 61, v2 = row - v1 * 61;
    wsb[PCAT_OFF + e] = (bf16)((c < 5) ? p1e[v1 * 5 + c] : p2e[v2 * 5 + (c - 5)]);
    return;
  }
  e -= 37210;
  if (e < 45056) {
    const int r = e / 704, c = e - r * 704;
    wsb[REMBB_OFF + e] = (r < NRELS && c < 690) ? (bf16)remb[r * 690 + c] : (bf16)0.0f;
    return;
  }
  e -= 45056;
  if (e < 49152) {
    const int oc = e / 192, k = e - oc * 192;
    wsb[CONVB_OFF + e] = (oc < OCC && k < 180) ? (bf16)convw[oc * 180 + k] : (bf16)0.0f;
    return;
  }
  e -= 49152;
  if (e < 8) wsb[ZOFF + e] = (bf16)0.0f;
}

__global__ __launch_bounds__(1024, 4)
void pcnn_bag(const int* __restrict__ words, const int* __restrict__ posi,
              const float* __restrict__ cb0, const float* __restrict__ cb1,
              const float* __restrict__ cb2, const float* __restrict__ rbias,
              const bf16* __restrict__ wsb, float* __restrict__ out)
{
  __shared__ __align__(16) bf16 xflat[2][7360];   // A[m][k] = xflat[m*60+k] (+60 lead pad)
  __shared__ __align__(16) bf16 fl_all[8][712];   // tanh feats per sentence (cols>=690 zero)
  __shared__ int widx[960];                       // word | pidx<<16 | piece<<28
  __shared__ float poolbuf[2][3][256];
  __shared__ float logits_l[8][64];

  const int t = threadIdx.x;
  const int b = blockIdx.x;
  const int wv = t >> 6;       // 0..15
  const int lane = t & 63;
  const int g = lane >> 4;
  const int cl = lane & 15;
  const int mh = wv >> 3;      // m-half: rows [mh*64, mh*64+64)
  const int ocp = wv & 7;      // oc-pair: tiles 2*ocp, 2*ocp+1 (32 oc)

  // ---- ids for the whole bag ----
  if (t < 960) {
    const int w = words[b * 960 + t];
    const int2 pp = *reinterpret_cast<const int2*>(posi + b * 1920 + 2 * t);
    const bool b0 = pp.x >= 30, b1 = pp.y >= 30;
    const int pc = (b0 && b1) ? 0 : ((!b0 && !b1) ? 2 : 1);
    widx[t] = w | ((pp.x * 61 + pp.y) << 16) | (pc << 28);
  }
  if (t < 60) { xflat[0][t] = (bf16)0.0f; xflat[1][t] = (bf16)0.0f; }
  if (t < 112) fl_all[t / 14][690 + (t % 14)] = (bf16)0.0f;

  // ---- conv weights (pre-padded bf16) -> registers: 12 frags = 48 VGPR ----
  FragU Bf[2][6];
  {
    const bf16* cwb = wsb + CONVB_OFF;
#pragma unroll
    for (int nt = 0; nt < 2; ++nt) {
      const int oc = ocp * 32 + nt * 16 + cl;
#pragma unroll
      for (int ks = 0; ks < 6; ++ks)
        Bf[nt][ks].v8 = *reinterpret_cast<const bf16x8*>(cwb + oc * 192 + ks * 32 + g * 8);
    }
  }

  // ---- per-thread bias/slot precompute for combine phase ----
  int pA = 0, ocA = 0;
  float biasA = 0.0f;
  if (t < 690) {
    pA = t / 230; ocA = t - pA * 230;
    biasA = (pA == 0 ? cb0 : pA == 1 ? cb1 : cb2)[ocA];
  }
  __syncthreads();  // widx ready

  // ---- async gather: sentence s -> xflat[nb]; tail lanes fetch zeros ----
  auto gather_one = [&](int s, int nb, int j) {
    const int q = j * 1024 + wv * 64 + lane;       // bf16-pair slot; dst elem = 60+2q
    const int qc = (q < 3600) ? q : 3599;
    const int l = qc / 30;
    const int c = qc - l * 30;
    const int wi = widx[s * 120 + l];
    const int word = wi & 0xFFFF;
    const int pidx = (wi >> 16) & 0xFFF;
    const bf16* srcd = (c < 25) ? (wsb + word * 50 + 2 * c)
                                : (wsb + PCAT_OFF + pidx * 10 + (2 * c - 50));
    const bf16* src = (q < 3600) ? srcd : (wsb + ZOFF);
    bf16* dst = &xflat[nb][60 + j * 2048 + wv * 128];  // wave-uniform; HW adds lane*4B
    __builtin_amdgcn_global_load_lds(
        (const __attribute__((address_space(1))) void*)src,
        (__attribute__((address_space(3))) void*)dst, 4, 0, 0);
  };
  auto issue_gather = [&](int s, int nb) {
#pragma unroll
    for (int j = 0; j < 3; ++j) gather_one(s, nb, j);
    if (wv < 9) gather_one(s, nb, 3);  // tail + zero-fill pad elems [7260,7355]
  };

  issue_gather(0, 0);
  asm volatile("s_waitcnt vmcnt(0)" ::: "memory");
  __syncthreads();

  // ---- per-sentence: conv GEMM + piecewise pool + tanh ----
  for (int s = 0; s < 8; ++s) {
    const int nb = s & 1;
    if (s < 7) issue_gather(s + 1, nb ^ 1);

    int mrow[4];
#pragma unroll
    for (int mt = 0; mt < 4; ++mt) {
      const int m = mh * 64 + mt * 16 + cl;
      mrow[mt] = (m < 120 ? m : 119) * 60;   // clamp pad rows (outputs discarded)
    }

    f32x4 acc[4][2];
    const f32x4 z4 = {0.f, 0.f, 0.f, 0.f};
#pragma unroll
    for (int mt = 0; mt < 4; ++mt) { acc[mt][0] = z4; acc[mt][1] = z4; }

#pragma unroll
    for (int ks = 0; ks < 6; ++ks) {
#pragma unroll
      for (int mt = 0; mt < 4; ++mt) {
        FragU a;
        const int idx = mrow[mt] + ks * 32 + g * 8;
        a.v4[0] = *reinterpret_cast<const bf16x4*>(&xflat[nb][idx]);
        a.v4[1] = *reinterpret_cast<const bf16x4*>(&xflat[nb][idx + 4]);
#pragma unroll
        for (int nt = 0; nt < 2; ++nt)
          acc[mt][nt] = __builtin_amdgcn_mfma_f32_16x16x32_bf16(
              a.v8, Bf[nt][ks].v8, acc[mt][nt], 0, 0, 0);
      }
    }

    // piecewise masked max (ref semantics: masked-out contributes 0)
    float pool[2][3];
#pragma unroll
    for (int nt = 0; nt < 2; ++nt) { pool[nt][0] = pool[nt][1] = pool[nt][2] = -INFINITY; }
#pragma unroll
    for (int mt = 0; mt < 4; ++mt) {
      const int l0 = mh * 64 + mt * 16 + g * 4;
      if (l0 < 120) {
        const int4 pv = *reinterpret_cast<const int4*>(&widx[s * 120 + l0]);
        const int pcs[4] = {(int)((unsigned)pv.x >> 28), (int)((unsigned)pv.y >> 28),
                            (int)((unsigned)pv.z >> 28), (int)((unsigned)pv.w >> 28)};
#pragma unroll
        for (int r = 0; r < 4; ++r) {
          const int p = pcs[r];
#pragma unroll
          for (int nt = 0; nt < 2; ++nt) {
            const float v = acc[mt][nt][r];
            pool[nt][0] = fmaxf(pool[nt][0], p == 0 ? v : 0.0f);
            pool[nt][1] = fmaxf(pool[nt][1], p == 1 ? v : 0.0f);
            pool[nt][2] = fmaxf(pool[nt][2], p == 2 ? v : 0.0f);
          }
        }
      }
    }
#pragma unroll
    for (int nt = 0; nt < 2; ++nt)
#pragma unroll
      for (int p = 0; p < 3; ++p) {
        float x = pool[nt][p];
        x = fmaxf(x, __shfl_xor(x, 16));
        x = fmaxf(x, __shfl_xor(x, 32));
        pool[nt][p] = x;
      }
    if (g == 0) {
#pragma unroll
      for (int nt = 0; nt < 2; ++nt) {
        const int oc = ocp * 32 + nt * 16 + cl;
        poolbuf[mh][0][oc] = pool[nt][0];
        poolbuf[mh][1][oc] = pool[nt][1];
        poolbuf[mh][2][oc] = pool[nt][2];
      }
    }
    __syncthreads();  // poolbuf ready

    if (t < 690)
      fl_all[s][t] = (bf16)tanhf(fmaxf(poolbuf[0][pA][ocA], poolbuf[1][pA][ocA]) + biasA);

    asm volatile("s_waitcnt vmcnt(0)" ::: "memory");  // gather(s+1) landed (per wave)
    __syncthreads();  // xflat[nb^1] ready, poolbuf free, fl_all[s] visible
  }

  // ---- batched logits GEMM: [8 sent x 704] @ rembb^T[704 x 64] ----
  if (wv < 4) {
    f32x4 lac = {0.f, 0.f, 0.f, 0.f};
    const bf16* brow = wsb + REMBB_OFF + (wv * 16 + cl) * 704 + g * 8;
    const bf16x8 zf = {(bf16)0.f, (bf16)0.f, (bf16)0.f, (bf16)0.f,
                       (bf16)0.f, (bf16)0.f, (bf16)0.f, (bf16)0.f};
#pragma unroll
    for (int ks = 0; ks < 22; ++ks) {
      bf16x8 afr = (cl < 8)
          ? *reinterpret_cast<const bf16x8*>(&fl_all[cl][ks * 32 + g * 8]) : zf;
      const bf16x8 bfr = *reinterpret_cast<const bf16x8*>(brow + ks * 32);
      lac = __builtin_amdgcn_mfma_f32_16x16x32_bf16(afr, bfr, lac, 0, 0, 0);
    }
    if (g < 2) {
      const int rel = wv * 16 + cl;
      const float bias = (rel < NRELS) ? rbias[rel] : 0.0f;
#pragma unroll
      for (int r = 0; r < 4; ++r)
        logits_l[g * 4 + r][rel] = lac[r] * 0.5f + bias;
    }
  }
  __syncthreads();

  // ---- per-wave softmax: wave wv handles sentence wv (wv<8) ----
  if (wv < 8) {
    const float x = (lane < NRELS) ? logits_l[wv][lane] : -INFINITY;
    float m = x;
#pragma unroll
    for (int off = 32; off; off >>= 1) m = fmaxf(m, __shfl_xor(m, off));
    const float e = (lane < NRELS) ? __expf(x - m) : 0.0f;
    float sm = e;
#pragma unroll
    for (int off = 32; off; off >>= 1) sm += __shfl_xor(sm, off);
    if (lane < NRELS) logits_l[wv][lane] = x - m - __logf(sm);
  }
  __syncthreads();

  // ---- fused bag-max ----
  if (t < NRELS) {
    float m = logits_l[0][t];
#pragma unroll
    for (int s2 = 1; s2 < 8; ++s2) m = fmaxf(m, logits_l[s2][t]);
    out[b * NRELS + t] = m;
  }
}

extern "C" void kernel_launch(void* const* d_in, const int* in_sizes, int n_in,
                              void* d_out, int out_size, void* d_ws, size_t ws_size,
                              hipStream_t stream) {
  const int* words  = (const int*)d_in[0];
  const int* posi   = (const int*)d_in[1];
  const float* w2v  = (const float*)d_in[2];
  const float* p1e  = (const float*)d_in[3];
  const float* p2e  = (const float*)d_in[4];
  const float* cw   = (const float*)d_in[5];
  const float* cb0  = (const float*)d_in[6];
  const float* cb1  = (const float*)d_in[7];
  const float* cb2  = (const float*)d_in[8];
  const float* remb = (const float*)d_in[9];
  const float* rbias= (const float*)d_in[10];
  bf16* wsb = (bf16*)d_ws;
  float* out = (float*)d_out;

  pcnn_prep<<<2955, 256, 0, stream>>>(w2v, p1e, p2e, remb, cw, wsb);
  pcnn_bag<<<1000, 1024, 0, stream>>>(words, posi, cb0, cb1, cb2, rbias, wsb, out);
}